// Round 6
// baseline (518.214 us; speedup 1.0000x reference)
//
#include <hip/hip_runtime.h>

#define BATCH 2048
#define IN    256
#define OUTD  256
#define NC    11   // NUM + K = 8 + 3

typedef __attribute__((ext_vector_type(4))) float f32x4;

// ---------- pre-pass: coefT[i][n][o] = coef[i][o][n] ----------
__global__ __launch_bounds__(256) void transpose_coef(
    const float* __restrict__ coef, float* __restrict__ coefT)
{
    __shared__ float tile[NC][OUTD];
    const int i = blockIdx.x;
    const int o = threadIdx.x;
    const float* src = coef + (size_t)i * OUTD * NC + o * NC;
    #pragma unroll
    for (int n = 0; n < NC; ++n) tile[n][o] = src[n];
    __syncthreads();
    float* dst = coefT + (size_t)i * NC * OUTD;
    #pragma unroll
    for (int n = 0; n < NC; ++n) dst[n * OUTD + o] = tile[n][o];
}

// ---------- main kernel: register-direct, barrier-free main loop ----------
__global__ __launch_bounds__(256, 6) void kan_main(
    const float* __restrict__ x, const float* __restrict__ coefT,
    const float* __restrict__ sb, const float* __restrict__ ss,
    const float* __restrict__ mk, float* __restrict__ out)
{
    __shared__ f32x4 v_s[IN];     // basis values per i
    __shared__ float base_s[IN];  // silu(xn)
    __shared__ int   comb_s[IN];  // i*NC*OUTD + idx*OUTD
    __shared__ float xn_s[IN];    // xn

    const int b = blockIdx.x;
    const int t = threadIdx.x;

    // ---- Phase A: per-input-dim scalars (thread = i) ----
    {
        float xv  = x[(size_t)b * IN + t];
        float xn  = tanhf(2.0f * xv);          // shift=0, scal=1
        float sig = 1.0f / (1.0f + expf(-xn));
        float base = xn * sig;
        float pos  = (xn + 1.0f) * 4.0f;       // h = 0.25
        float fidx = fminf(fmaxf(floorf(pos), 0.0f), 7.0f);
        float u    = pos - fidx;
        int   idx  = (int)fidx;
        float u2 = u * u, u3 = u2 * u;
        const float c6 = 1.0f / 6.0f;
        f32x4 v;
        v.x = (1.0f - 3.0f * u + 3.0f * u2 - u3) * c6;
        v.y = (4.0f - 6.0f * u2 + 3.0f * u3) * c6;
        v.z = (1.0f + 3.0f * u + 3.0f * u2 - 3.0f * u3) * c6;
        v.w = u3 * c6;
        v_s[t]    = v;
        base_s[t] = base;
        comb_s[t] = t * (NC * OUTD) + idx * OUTD;
        xn_s[t]   = xn;
    }
    __syncthreads();

    // output layout (f32): y | preacts | postacts | postspline
    float* y    = out;
    float* pre  = out + (size_t)BATCH * OUTD;
    float* pact = pre  + (size_t)BATCH * OUTD * IN;
    float* pspl = pact + (size_t)BATCH * OUTD * IN;

    const int oo = t >> 2;          // 0..63
    const int iq = (t & 3) * 4;     // i-quad offset within 16-chunk
    const size_t bbase = (size_t)b * OUTD * IN;

    float yacc0 = 0.f, yacc1 = 0.f, yacc2 = 0.f, yacc3 = 0.f;

    for (int ic = 0; ic < IN / 16; ++ic) {
        const int ibase = ic * 16 + iq;
        // per-i data from LDS, reused across the 4 o-values
        f32x4 vq[4]; float bq[4]; int cq[4]; f32x4 xq;
        #pragma unroll
        for (int ii = 0; ii < 4; ++ii) {
            const int i = ibase + ii;
            vq[ii] = v_s[i];
            bq[ii] = base_s[i];
            cq[ii] = comb_s[i];
            xq[ii] = xn_s[i];
        }
        #pragma unroll
        for (int c = 0; c < 4; ++c) {
            const int o = c * 64 + oo;
            f32x4 ps, pa;
            float ya = 0.f;
            #pragma unroll
            for (int ii = 0; ii < 4; ++ii) {
                const int i = ibase + ii;
                const float* cp = coefT + cq[ii] + o;
                float spl = cp[0]        * vq[ii].x + cp[OUTD]     * vq[ii].y
                          + cp[OUTD * 2] * vq[ii].z + cp[OUTD * 3] * vq[ii].w;
                const int io = i * OUTD + o;
                float yf = mk[io] * (sb[io] * bq[ii] + ss[io] * spl);
                ya += yf;
                ps[ii] = spl;
                pa[ii] = yf;
            }
            if (c == 0) yacc0 += ya; else if (c == 1) yacc1 += ya;
            else if (c == 2) yacc2 += ya; else yacc3 += ya;
            const size_t g = bbase + (size_t)o * IN + ibase;
            __builtin_nontemporal_store(ps, (f32x4*)(pspl + g));
            __builtin_nontemporal_store(pa, (f32x4*)(pact + g));
            __builtin_nontemporal_store(xq, (f32x4*)(pre  + g));
        }
    }

    // ---- y: reduce over the 4 lanes sharing each o ----
    float ya[4] = {yacc0, yacc1, yacc2, yacc3};
    #pragma unroll
    for (int c = 0; c < 4; ++c) {
        float v = ya[c];
        v += __shfl_xor(v, 1);
        v += __shfl_xor(v, 2);
        if ((t & 3) == 0) y[(size_t)b * OUTD + c * 64 + oo] = v;
    }
}

// ---------- fallback (direct gather, no scratch needed) ----------
__global__ __launch_bounds__(256, 4) void kan_main_direct(
    const float* __restrict__ x, const float* __restrict__ coef,
    const float* __restrict__ sb, const float* __restrict__ ss,
    const float* __restrict__ mk, float* __restrict__ out)
{
    __shared__ f32x4 v_s[IN];
    __shared__ float base_s[IN];
    __shared__ int   comb_s[IN];
    __shared__ float xn_s[IN];

    const int b = blockIdx.x;
    const int t = threadIdx.x;
    {
        float xv  = x[(size_t)b * IN + t];
        float xn  = tanhf(2.0f * xv);
        float sig = 1.0f / (1.0f + expf(-xn));
        float base = xn * sig;
        float pos  = (xn + 1.0f) * 4.0f;
        float fidx = fminf(fmaxf(floorf(pos), 0.0f), 7.0f);
        float u    = pos - fidx;
        int   idx  = (int)fidx;
        float u2 = u * u, u3 = u2 * u;
        const float c6 = 1.0f / 6.0f;
        f32x4 v;
        v.x = (1.0f - 3.0f * u + 3.0f * u2 - u3) * c6;
        v.y = (4.0f - 6.0f * u2 + 3.0f * u3) * c6;
        v.z = (1.0f + 3.0f * u + 3.0f * u2 - 3.0f * u3) * c6;
        v.w = u3 * c6;
        v_s[t] = v; base_s[t] = base;
        comb_s[t] = t * (OUTD * NC) + idx;
        xn_s[t] = xn;
    }
    __syncthreads();

    float* y    = out;
    float* pre  = out + (size_t)BATCH * OUTD;
    float* pact = pre  + (size_t)BATCH * OUTD * IN;
    float* pspl = pact + (size_t)BATCH * OUTD * IN;

    const int oo = t >> 2;
    const int iq = (t & 3) * 4;
    const size_t bbase = (size_t)b * OUTD * IN;
    float yaccs[4] = {0.f, 0.f, 0.f, 0.f};

    for (int ic = 0; ic < IN / 16; ++ic) {
        const int ibase = ic * 16 + iq;
        f32x4 vq[4]; float bq[4]; int cq[4]; f32x4 xq;
        #pragma unroll
        for (int ii = 0; ii < 4; ++ii) {
            const int i = ibase + ii;
            vq[ii] = v_s[i]; bq[ii] = base_s[i]; cq[ii] = comb_s[i]; xq[ii] = xn_s[i];
        }
        #pragma unroll
        for (int c = 0; c < 4; ++c) {
            const int o = c * 64 + oo;
            f32x4 ps, pa;
            float ya = 0.f;
            #pragma unroll
            for (int ii = 0; ii < 4; ++ii) {
                const int i = ibase + ii;
                const float* cp = coef + cq[ii] + o * NC;
                float spl = cp[0] * vq[ii].x + cp[1] * vq[ii].y
                          + cp[2] * vq[ii].z + cp[3] * vq[ii].w;
                const int io = i * OUTD + o;
                float yf = mk[io] * (sb[io] * bq[ii] + ss[io] * spl);
                ya += yf;
                ps[ii] = spl; pa[ii] = yf;
            }
            yaccs[c] += ya;
            const size_t g = bbase + (size_t)o * IN + ibase;
            __builtin_nontemporal_store(ps, (f32x4*)(pspl + g));
            __builtin_nontemporal_store(pa, (f32x4*)(pact + g));
            __builtin_nontemporal_store(xq, (f32x4*)(pre  + g));
        }
    }
    #pragma unroll
    for (int c = 0; c < 4; ++c) {
        float v = yaccs[c];
        v += __shfl_xor(v, 1);
        v += __shfl_xor(v, 2);
        if ((t & 3) == 0) y[(size_t)b * OUTD + c * 64 + oo] = v;
    }
}

extern "C" void kernel_launch(void* const* d_in, const int* in_sizes, int n_in,
                              void* d_out, int out_size, void* d_ws, size_t ws_size,
                              hipStream_t stream) {
    const float* x    = (const float*)d_in[0];
    const float* coef = (const float*)d_in[1];
    const float* sb   = (const float*)d_in[2];
    const float* ss   = (const float*)d_in[3];
    const float* mk   = (const float*)d_in[4];
    float* out = (float*)d_out;

    const size_t coefT_bytes = (size_t)IN * NC * OUTD * sizeof(float);
    if (ws_size >= coefT_bytes) {
        float* coefT = (float*)d_ws;
        transpose_coef<<<IN, 256, 0, stream>>>(coef, coefT);
        kan_main<<<BATCH, 256, 0, stream>>>(x, coefT, sb, ss, mk, out);
    } else {
        kan_main_direct<<<BATCH, 256, 0, stream>>>(x, coef, sb, ss, mk, out);
    }
}

// Round 7
// 495.447 us; speedup vs baseline: 1.0460x; 1.0460x over previous
//
#include <hip/hip_runtime.h>

#define BATCH 2048
#define IN    256
#define OUTD  256
#define NC    11   // NUM + K = 8 + 3
#define ICP   17   // padded tile row stride (2-way bank aliasing = free)

typedef __attribute__((ext_vector_type(4))) float f32x4;

// ---------- pre-pass: coefT[i][n][o] = coef[i][o][n] ----------
__global__ __launch_bounds__(256) void transpose_coef(
    const float* __restrict__ coef, float* __restrict__ coefT)
{
    __shared__ float tile[NC][OUTD];
    const int i = blockIdx.x;
    const int o = threadIdx.x;
    const float* src = coef + (size_t)i * OUTD * NC + o * NC;
    #pragma unroll
    for (int n = 0; n < NC; ++n) tile[n][o] = src[n];
    __syncthreads();
    float* dst = coefT + (size_t)i * NC * OUTD;
    #pragma unroll
    for (int n = 0; n < NC; ++n) dst[n * OUTD + o] = tile[n][o];
}

// ---------- main kernel: o=t reads, wave-private LDS transpose, 0 main-loop barriers ----------
__global__ __launch_bounds__(256, 3) void kan_main(
    const float* __restrict__ x, const float* __restrict__ coefT,
    const float* __restrict__ sb, const float* __restrict__ ss,
    const float* __restrict__ mk, float* __restrict__ out)
{
    __shared__ f32x4 v_s[IN];
    __shared__ float base_s[IN];
    __shared__ int   comb_s[IN];       // i*NC*OUTD + idx*OUTD
    __shared__ float xn_s[IN];
    __shared__ float ps_t[OUTD * ICP]; // wave w owns rows [64w, 64w+64)
    __shared__ float pa_t[OUTD * ICP];

    const int b = blockIdx.x;
    const int t = threadIdx.x;

    // ---- Phase A: per-input-dim scalars (thread = i) ----
    {
        float xv  = x[(size_t)b * IN + t];
        float xn  = tanhf(2.0f * xv);          // shift=0, scal=1
        float sig = 1.0f / (1.0f + expf(-xn));
        float base = xn * sig;
        float pos  = (xn + 1.0f) * 4.0f;       // h = 0.25
        float fidx = fminf(fmaxf(floorf(pos), 0.0f), 7.0f);
        float u    = pos - fidx;
        int   idx  = (int)fidx;
        float u2 = u * u, u3 = u2 * u;
        const float c6 = 1.0f / 6.0f;
        f32x4 v;
        v.x = (1.0f - 3.0f * u + 3.0f * u2 - u3) * c6;
        v.y = (4.0f - 6.0f * u2 + 3.0f * u3) * c6;
        v.z = (1.0f + 3.0f * u + 3.0f * u2 - 3.0f * u3) * c6;
        v.w = u3 * c6;
        v_s[t]    = v;
        base_s[t] = base;
        comb_s[t] = t * (NC * OUTD) + idx * OUTD;
        xn_s[t]   = xn;
    }
    __syncthreads();   // the ONLY block-wide barrier

    float* y    = out;
    float* pre  = out + (size_t)BATCH * OUTD;
    float* pact = pre  + (size_t)BATCH * OUTD * IN;
    float* pspl = pact + (size_t)BATCH * OUTD * IN;

    const int o  = t;                  // reads stay lane-consecutive in o
    const int w  = t >> 6;             // wave id
    const int lq = (t & 63) >> 2;      // 0..15: row within 16-row group
    const int lr = t & 3;              // 0..3 : 16B quad within 64B row chunk
    const int rbase = w * 64;          // wave-private tile row range
    const size_t bbase = (size_t)b * OUTD * IN;

    float yacc = 0.0f;

    for (int ic = 0; ic < IN / 16; ++ic) {
        const int i0 = ic * 16;
        // ---- compute 16 i-values into wave-private tile rows ----
        #pragma unroll
        for (int ii = 0; ii < 16; ++ii) {
            const int i = i0 + ii;
            f32x4 v = v_s[i];
            const float* cp = coefT + comb_s[i] + o;   // 256B contiguous / wave
            float spl = cp[0]        * v.x + cp[OUTD]     * v.y
                      + cp[OUTD * 2] * v.z + cp[OUTD * 3] * v.w;
            const int io = i * OUTD + o;
            float yf = mk[io] * (sb[io] * base_s[i] + ss[io] * spl);
            yacc += yf;
            ps_t[o * ICP + ii] = spl;
            pa_t[o * ICP + ii] = yf;
        }
        // ---- wave-private writeback (no barrier; lgkmcnt orders ds ops) ----
        f32x4 xq;
        xq.x = xn_s[i0 + lr * 4 + 0];
        xq.y = xn_s[i0 + lr * 4 + 1];
        xq.z = xn_s[i0 + lr * 4 + 2];
        xq.w = xn_s[i0 + lr * 4 + 3];
        #pragma unroll
        for (int c = 0; c < 4; ++c) {
            const int oo = rbase + c * 16 + lq;
            const int la = oo * ICP + lr * 4;
            f32x4 vps, vpa;
            vps.x = ps_t[la];   vps.y = ps_t[la+1];
            vps.z = ps_t[la+2]; vps.w = ps_t[la+3];
            vpa.x = pa_t[la];   vpa.y = pa_t[la+1];
            vpa.z = pa_t[la+2]; vpa.w = pa_t[la+3];
            const size_t g = bbase + (size_t)oo * IN + i0 + lr * 4;
            __builtin_nontemporal_store(vps, (f32x4*)(pspl + g));
            __builtin_nontemporal_store(vpa, (f32x4*)(pact + g));
            __builtin_nontemporal_store(xq,  (f32x4*)(pre  + g));
        }
    }

    y[(size_t)b * OUTD + o] = yacc;
}

// ---------- fallback (direct gather, block-wide tile + barriers) ----------
__global__ __launch_bounds__(256, 3) void kan_main_direct(
    const float* __restrict__ x, const float* __restrict__ coef,
    const float* __restrict__ sb, const float* __restrict__ ss,
    const float* __restrict__ mk, float* __restrict__ out)
{
    __shared__ f32x4 v_s[IN];
    __shared__ float base_s[IN];
    __shared__ int   comb_s[IN];
    __shared__ float xn_s[IN];
    __shared__ float ps_t[OUTD * ICP];
    __shared__ float pa_t[OUTD * ICP];

    const int b = blockIdx.x;
    const int t = threadIdx.x;
    {
        float xv  = x[(size_t)b * IN + t];
        float xn  = tanhf(2.0f * xv);
        float sig = 1.0f / (1.0f + expf(-xn));
        float base = xn * sig;
        float pos  = (xn + 1.0f) * 4.0f;
        float fidx = fminf(fmaxf(floorf(pos), 0.0f), 7.0f);
        float u    = pos - fidx;
        int   idx  = (int)fidx;
        float u2 = u * u, u3 = u2 * u;
        const float c6 = 1.0f / 6.0f;
        f32x4 v;
        v.x = (1.0f - 3.0f * u + 3.0f * u2 - u3) * c6;
        v.y = (4.0f - 6.0f * u2 + 3.0f * u3) * c6;
        v.z = (1.0f + 3.0f * u + 3.0f * u2 - 3.0f * u3) * c6;
        v.w = u3 * c6;
        v_s[t] = v; base_s[t] = base;
        comb_s[t] = t * (OUTD * NC) + idx;
        xn_s[t] = xn;
    }
    __syncthreads();

    float* y    = out;
    float* pre  = out + (size_t)BATCH * OUTD;
    float* pact = pre  + (size_t)BATCH * OUTD * IN;
    float* pspl = pact + (size_t)BATCH * OUTD * IN;
    {
        f32x4 myxn = ((const f32x4*)xn_s)[t & 63];
        f32x4* dst = (f32x4*)(pre + (size_t)b * OUTD * IN);
        #pragma unroll 8
        for (int c = 0; c < 64; ++c)
            __builtin_nontemporal_store(myxn, dst + c * 256 + t);
    }
    float yacc = 0.0f;
    const int o = t;
    const int oNC = o * NC;
    const size_t bbase = (size_t)b * OUTD * IN;
    for (int ic = 0; ic < IN / 16; ++ic) {
        #pragma unroll
        for (int ii = 0; ii < 16; ++ii) {
            const int i = ic * 16 + ii;
            f32x4 v = v_s[i];
            const float* cp = coef + comb_s[i] + oNC;
            float spl = cp[0] * v.x + cp[1] * v.y + cp[2] * v.z + cp[3] * v.w;
            const int io = i * OUTD + o;
            float yf = mk[io] * (sb[io] * base_s[i] + ss[io] * spl);
            yacc += yf;
            ps_t[o * ICP + ii] = spl;
            pa_t[o * ICP + ii] = yf;
        }
        __syncthreads();
        #pragma unroll
        for (int c = 0; c < 4; ++c) {
            const int f  = c * 256 + t;
            const int oo = f >> 2;
            const int i4 = (f & 3) * 4;
            const int la = oo * ICP + i4;
            f32x4 vps, vpa;
            vps.x = ps_t[la]; vps.y = ps_t[la+1]; vps.z = ps_t[la+2]; vps.w = ps_t[la+3];
            vpa.x = pa_t[la]; vpa.y = pa_t[la+1]; vpa.z = pa_t[la+2]; vpa.w = pa_t[la+3];
            const size_t g = bbase + (size_t)oo * IN + ic * 16 + i4;
            __builtin_nontemporal_store(vps, (f32x4*)(pspl + g));
            __builtin_nontemporal_store(vpa, (f32x4*)(pact + g));
        }
        __syncthreads();
    }
    y[(size_t)b * OUTD + o] = yacc;
}

extern "C" void kernel_launch(void* const* d_in, const int* in_sizes, int n_in,
                              void* d_out, int out_size, void* d_ws, size_t ws_size,
                              hipStream_t stream) {
    const float* x    = (const float*)d_in[0];
    const float* coef = (const float*)d_in[1];
    const float* sb   = (const float*)d_in[2];
    const float* ss   = (const float*)d_in[3];
    const float* mk   = (const float*)d_in[4];
    float* out = (float*)d_out;

    const size_t coefT_bytes = (size_t)IN * NC * OUTD * sizeof(float);
    if (ws_size >= coefT_bytes) {
        float* coefT = (float*)d_ws;
        transpose_coef<<<IN, 256, 0, stream>>>(coef, coefT);
        kan_main<<<BATCH, 256, 0, stream>>>(x, coefT, sb, ss, mk, out);
    } else {
        kan_main_direct<<<BATCH, 256, 0, stream>>>(x, coef, sb, ss, mk, out);
    }
}

// Round 8
// 425.591 us; speedup vs baseline: 1.2176x; 1.1641x over previous
//
#include <hip/hip_runtime.h>

#define BATCH 2048
#define IN    256
#define OUTD  256
#define NC    11   // NUM + K = 8 + 3
#define IC    16   // i-chunk staged in LDS
#define ICP   17   // padded tile row stride (2-way bank aliasing = free)

typedef __attribute__((ext_vector_type(4))) float f32x4;

// LDS-only barrier: does NOT drain vmcnt, so in-flight global (NT) stores and
// loads pipeline across chunks. lgkmcnt(0) retires this wave's ds ops before
// s_barrier -> cross-wave LDS RAW/WAR ordering is preserved (LDS is CU-local).
#define LDS_BARRIER()                                              \
    do {                                                           \
        asm volatile("s_waitcnt lgkmcnt(0)" ::: "memory");         \
        __builtin_amdgcn_s_barrier();                              \
    } while (0)

// ---------- pre-pass: coefT[i][n][o] = coef[i][o][n] ----------
__global__ __launch_bounds__(256) void transpose_coef(
    const float* __restrict__ coef, float* __restrict__ coefT)
{
    __shared__ float tile[NC][OUTD];
    const int i = blockIdx.x;
    const int o = threadIdx.x;
    const float* src = coef + (size_t)i * OUTD * NC + o * NC;
    #pragma unroll
    for (int n = 0; n < NC; ++n) tile[n][o] = src[n];
    __syncthreads();
    float* dst = coefT + (size_t)i * NC * OUTD;
    #pragma unroll
    for (int n = 0; n < NC; ++n) dst[n * OUTD + o] = tile[n][o];
}

// ---------- main kernel (r5 structure; in-loop barriers are LDS-only) ----------
__global__ __launch_bounds__(256, 3) void kan_main(
    const float* __restrict__ x, const float* __restrict__ coefT,
    const float* __restrict__ sb, const float* __restrict__ ss,
    const float* __restrict__ mk, float* __restrict__ out)
{
    __shared__ f32x4 v_s[IN];
    __shared__ float base_s[IN];
    __shared__ int   comb_s[IN];       // i*NC*OUTD + idx*OUTD
    __shared__ float xn_s[IN];
    __shared__ float ps_t[OUTD * ICP];
    __shared__ float pa_t[OUTD * ICP];

    const int b = blockIdx.x;
    const int t = threadIdx.x;

    {
        float xv  = x[(size_t)b * IN + t];
        float xn  = tanhf(2.0f * xv);          // shift=0, scal=1
        float sig = 1.0f / (1.0f + expf(-xn));
        float base = xn * sig;
        float pos  = (xn + 1.0f) * 4.0f;       // h = 0.25
        float fidx = fminf(fmaxf(floorf(pos), 0.0f), 7.0f);
        float u    = pos - fidx;
        int   idx  = (int)fidx;
        float u2 = u * u, u3 = u2 * u;
        const float c6 = 1.0f / 6.0f;
        f32x4 v;
        v.x = (1.0f - 3.0f * u + 3.0f * u2 - u3) * c6;
        v.y = (4.0f - 6.0f * u2 + 3.0f * u3) * c6;
        v.z = (1.0f + 3.0f * u + 3.0f * u2 - 3.0f * u3) * c6;
        v.w = u3 * c6;
        v_s[t]    = v;
        base_s[t] = base;
        comb_s[t] = t * (NC * OUTD) + idx * OUTD;
        xn_s[t]   = xn;
    }
    __syncthreads();   // once per block; cost negligible

    float* y    = out;
    float* pre  = out + (size_t)BATCH * OUTD;
    float* pact = pre  + (size_t)BATCH * OUTD * IN;
    float* pspl = pact + (size_t)BATCH * OUTD * IN;

    // preacts: upfront contiguous burst (r5's proven-best geometry)
    {
        f32x4 myxn = ((const f32x4*)xn_s)[t & 63];
        f32x4* dst = (f32x4*)(pre + (size_t)b * OUTD * IN);
        #pragma unroll 8
        for (int c = 0; c < 64; ++c)
            __builtin_nontemporal_store(myxn, dst + c * 256 + t);
    }

    float yacc = 0.0f;
    const int o = t;
    const size_t bbase = (size_t)b * OUTD * IN;

    for (int ic = 0; ic < IN / IC; ++ic) {
        #pragma unroll
        for (int ii = 0; ii < IC; ++ii) {
            const int i = ic * IC + ii;
            f32x4 v = v_s[i];
            const float* cp = coefT + comb_s[i] + o;   // lane-consecutive
            float spl = cp[0]        * v.x + cp[OUTD]     * v.y
                      + cp[OUTD * 2] * v.z + cp[OUTD * 3] * v.w;
            const int io = i * OUTD + o;
            float yf = mk[io] * (sb[io] * base_s[i] + ss[io] * spl);
            yacc += yf;
            ps_t[o * ICP + ii] = spl;
            pa_t[o * ICP + ii] = yf;
        }
        LDS_BARRIER();   // RAW: LDS-only drain, NT stores stay in flight
        #pragma unroll
        for (int c = 0; c < 4; ++c) {
            const int f  = c * 256 + t;
            const int oo = f >> 2;
            const int i4 = (f & 3) * 4;
            const int la = oo * ICP + i4;
            f32x4 vps, vpa;
            vps.x = ps_t[la]; vps.y = ps_t[la+1]; vps.z = ps_t[la+2]; vps.w = ps_t[la+3];
            vpa.x = pa_t[la]; vpa.y = pa_t[la+1]; vpa.z = pa_t[la+2]; vpa.w = pa_t[la+3];
            const size_t g = bbase + (size_t)oo * IN + ic * IC + i4;
            __builtin_nontemporal_store(vps, (f32x4*)(pspl + g));
            __builtin_nontemporal_store(vpa, (f32x4*)(pact + g));
        }
        LDS_BARRIER();   // WAR: reads retired before next chunk's writes
    }

    y[(size_t)b * OUTD + o] = yacc;
}

// ---------- fallback (direct gather, no scratch needed) ----------
__global__ __launch_bounds__(256, 3) void kan_main_direct(
    const float* __restrict__ x, const float* __restrict__ coef,
    const float* __restrict__ sb, const float* __restrict__ ss,
    const float* __restrict__ mk, float* __restrict__ out)
{
    __shared__ f32x4 v_s[IN];
    __shared__ float base_s[IN];
    __shared__ int   comb_s[IN];
    __shared__ float xn_s[IN];
    __shared__ float ps_t[OUTD * ICP];
    __shared__ float pa_t[OUTD * ICP];

    const int b = blockIdx.x;
    const int t = threadIdx.x;
    {
        float xv  = x[(size_t)b * IN + t];
        float xn  = tanhf(2.0f * xv);
        float sig = 1.0f / (1.0f + expf(-xn));
        float base = xn * sig;
        float pos  = (xn + 1.0f) * 4.0f;
        float fidx = fminf(fmaxf(floorf(pos), 0.0f), 7.0f);
        float u    = pos - fidx;
        int   idx  = (int)fidx;
        float u2 = u * u, u3 = u2 * u;
        const float c6 = 1.0f / 6.0f;
        f32x4 v;
        v.x = (1.0f - 3.0f * u + 3.0f * u2 - u3) * c6;
        v.y = (4.0f - 6.0f * u2 + 3.0f * u3) * c6;
        v.z = (1.0f + 3.0f * u + 3.0f * u2 - 3.0f * u3) * c6;
        v.w = u3 * c6;
        v_s[t] = v; base_s[t] = base;
        comb_s[t] = t * (OUTD * NC) + idx;
        xn_s[t] = xn;
    }
    __syncthreads();

    float* y    = out;
    float* pre  = out + (size_t)BATCH * OUTD;
    float* pact = pre  + (size_t)BATCH * OUTD * IN;
    float* pspl = pact + (size_t)BATCH * OUTD * IN;
    {
        f32x4 myxn = ((const f32x4*)xn_s)[t & 63];
        f32x4* dst = (f32x4*)(pre + (size_t)b * OUTD * IN);
        #pragma unroll 8
        for (int c = 0; c < 64; ++c)
            __builtin_nontemporal_store(myxn, dst + c * 256 + t);
    }
    float yacc = 0.0f;
    const int o = t;
    const int oNC = o * NC;
    const size_t bbase = (size_t)b * OUTD * IN;
    for (int ic = 0; ic < IN / IC; ++ic) {
        #pragma unroll
        for (int ii = 0; ii < IC; ++ii) {
            const int i = ic * IC + ii;
            f32x4 v = v_s[i];
            const float* cp = coef + comb_s[i] + oNC;
            float spl = cp[0] * v.x + cp[1] * v.y + cp[2] * v.z + cp[3] * v.w;
            const int io = i * OUTD + o;
            float yf = mk[io] * (sb[io] * base_s[i] + ss[io] * spl);
            yacc += yf;
            ps_t[o * ICP + ii] = spl;
            pa_t[o * ICP + ii] = yf;
        }
        LDS_BARRIER();
        #pragma unroll
        for (int c = 0; c < 4; ++c) {
            const int f  = c * 256 + t;
            const int oo = f >> 2;
            const int i4 = (f & 3) * 4;
            const int la = oo * ICP + i4;
            f32x4 vps, vpa;
            vps.x = ps_t[la]; vps.y = ps_t[la+1]; vps.z = ps_t[la+2]; vps.w = ps_t[la+3];
            vpa.x = pa_t[la]; vpa.y = pa_t[la+1]; vpa.z = pa_t[la+2]; vpa.w = pa_t[la+3];
            const size_t g = bbase + (size_t)oo * IN + ic * IC + i4;
            __builtin_nontemporal_store(vps, (f32x4*)(pspl + g));
            __builtin_nontemporal_store(vpa, (f32x4*)(pact + g));
        }
        LDS_BARRIER();
    }
    y[(size_t)b * OUTD + o] = yacc;
}

extern "C" void kernel_launch(void* const* d_in, const int* in_sizes, int n_in,
                              void* d_out, int out_size, void* d_ws, size_t ws_size,
                              hipStream_t stream) {
    const float* x    = (const float*)d_in[0];
    const float* coef = (const float*)d_in[1];
    const float* sb   = (const float*)d_in[2];
    const float* ss   = (const float*)d_in[3];
    const float* mk   = (const float*)d_in[4];
    float* out = (float*)d_out;

    const size_t coefT_bytes = (size_t)IN * NC * OUTD * sizeof(float);
    if (ws_size >= coefT_bytes) {
        float* coefT = (float*)d_ws;
        transpose_coef<<<IN, 256, 0, stream>>>(coef, coefT);
        kan_main<<<BATCH, 256, 0, stream>>>(x, coefT, sb, ss, mk, out);
    } else {
        kan_main_direct<<<BATCH, 256, 0, stream>>>(x, coef, sb, ss, mk, out);
    }
}